// Round 7
// baseline (524.520 us; speedup 1.0000x reference)
//
#include <hip/hip_runtime.h>
#include <hip/hip_bf16.h>
#include <hip/hip_cooperative_groups.h>
#include <math.h>

namespace cg = cooperative_groups;

#define N_NODES 50000
#define N_EDGES 800000
#define FIN 128
#define FOUT 64
#define NH 8
#define ALPHA 0.2f
#define HSTRIDE (NH * FOUT)  // 512
#define SCAN_B 196           // ceil(50000/256)
#define BUILD_GRID 512

typedef __attribute__((ext_vector_type(8))) short bf16x8;
typedef __attribute__((ext_vector_type(4))) float f32x4;

__device__ __forceinline__ unsigned pack_bf2(float lo, float hi) {
    __hip_bfloat162 b = __float22bfloat162_rn(make_float2(lo, hi));
    return *(unsigned*)&b;
}

// ---------------- Cooperative build kernel: prep | hist | scan | fill in one launch.
__global__ __launch_bounds__(256, 2) void gat_build(const float* __restrict__ x,
                                                    const float* __restrict__ W,
                                                    const float* __restrict__ a,
                                                    const int* __restrict__ src,
                                                    const int* __restrict__ dst,
                                                    unsigned* __restrict__ xbf,
                                                    unsigned* __restrict__ bpt,
                                                    float* __restrict__ aperm,
                                                    int* __restrict__ deg,
                                                    int* __restrict__ bsum,
                                                    int* __restrict__ row_start,
                                                    int* __restrict__ cursor,
                                                    int* __restrict__ csr_dst) {
    cg::grid_group grid = cg::this_grid();
    const int t   = threadIdx.x;
    const int b   = blockIdx.x;
    const int tid = b * 256 + t;
    const int T   = BUILD_GRID * 256;   // 131072

    // ---- P0: x->bf16, W->BpT, a->aperm, deg=0
    for (int i = tid; i < N_NODES * FIN / 8; i += T) {
        const size_t ii = (size_t)i * 8;
        const float4 v0 = *(const float4*)(x + ii);
        const float4 v1 = *(const float4*)(x + ii + 4);
        uint4 o;
        o.x = pack_bf2(v0.x, v0.y);
        o.y = pack_bf2(v0.z, v0.w);
        o.z = pack_bf2(v1.x, v1.y);
        o.w = pack_bf2(v1.z, v1.w);
        *(uint4*)(xbf + (size_t)i * 4) = o;
    }
    if (tid < HSTRIDE * 32) {           // 16384: BpT
        const int dcol = tid >> 5;
        const int kq   = tid & 31;
        const int head = dcol & 7, col = dcol >> 3;
        const float* wp = W + (size_t)head * (FIN * FOUT) + (size_t)(kq * 4) * FOUT + col;
        uint2 pk;
        pk.x = pack_bf2(wp[0],        wp[FOUT]);
        pk.y = pack_bf2(wp[2 * FOUT], wp[3 * FOUT]);
        *(uint2*)(bpt + (size_t)dcol * (FIN / 2) + kq * 2) = pk;
    }
    if (tid < 2 * HSTRIDE) {            // 1024: aperm
        const int tab  = tid >> 9;
        const int dcol = tid & 511;
        aperm[tid] = a[(dcol & 7) * (2 * FOUT) + tab * FOUT + (dcol >> 3)];
    }
    for (int i = tid; i < N_NODES; i += T) deg[i] = 0;

    grid.sync();

    // ---- P1: degree histogram (2 edges per iter)
    for (int i = tid; i < N_EDGES / 2; i += T) {
        const int2 s2 = *(const int2*)(src + (size_t)i * 2);
        atomicAdd(&deg[s2.x], 1);
        atomicAdd(&deg[s2.y], 1);
    }

    grid.sync();

    // ---- P2: per-256-segment sums
    __shared__ int sm[256];
    if (b < SCAN_B) {
        const int gid = b * 256 + t;
        sm[t] = (gid < N_NODES) ? deg[gid] : 0;
        __syncthreads();
#pragma unroll
        for (int off = 128; off > 0; off >>= 1) {
            if (t < off) sm[t] += sm[t + off];
            __syncthreads();
        }
        if (t == 0) bsum[b] = sm[0];
    }

    grid.sync();

    // ---- P3: redundant partial-scan + segment scan -> row_start / cursor
    if (b < SCAN_B) {
        __shared__ int smp[256];
        const int pv = (t < SCAN_B) ? bsum[t] : 0;
        smp[t] = pv;
        __syncthreads();
        for (int off = 1; off < 256; off <<= 1) {
            const int u = (t >= off) ? smp[t - off] : 0;
            __syncthreads();
            smp[t] += u;
            __syncthreads();
        }
        const int base = (b > 0) ? smp[b - 1] : 0;   // exclusive block prefix

        const int gid = b * 256 + t;
        const int v   = (gid < N_NODES) ? deg[gid] : 0;
        sm[t] = v;
        __syncthreads();
        for (int off = 1; off < 256; off <<= 1) {
            const int u = (t >= off) ? sm[t - off] : 0;
            __syncthreads();
            sm[t] += u;
            __syncthreads();
        }
        if (gid < N_NODES) {
            const int rs = base + sm[t] - v;
            row_start[gid] = rs;
            cursor[gid]    = rs;
        }
        if (b == 0 && t == 0) row_start[N_NODES] = N_EDGES;
    }

    grid.sync();

    // ---- P4: fill CSR dst lists
    for (int i = tid; i < N_EDGES; i += T) {
        const int pos = atomicAdd(&cursor[src[i]], 1);
        csr_dst[pos] = dst[i];
    }
}

// ---------------- MFMA projection + fused scores (unchanged from round 6).
__global__ __launch_bounds__(256) void gat_proj(const unsigned short* __restrict__ xbf,
                                                const unsigned short* __restrict__ bpt,
                                                const float* __restrict__ aperm,
                                                unsigned short* __restrict__ h2,
                                                float* __restrict__ ssrc,
                                                float* __restrict__ sdst) {
    const int lane = threadIdx.x & 63;
    const int wid  = blockIdx.x * 4 + (threadIdx.x >> 6);
    const int m0   = wid * 32;
    const int l15  = lane & 15;
    const int g    = lane >> 4;

    bf16x8 xf[2][4];
#pragma unroll
    for (int nh = 0; nh < 2; ++nh) {
        int node = m0 + nh * 16 + l15;
        if (node > N_NODES - 1) node = N_NODES - 1;
        const unsigned short* p = xbf + (size_t)node * FIN + g * 8;
#pragma unroll
        for (int ks = 0; ks < 4; ++ks)
            xf[nh][ks] = *(const bf16x8*)(p + ks * 32);
    }

    float sc1[2][4], sc2[2][4];
#pragma unroll
    for (int nh = 0; nh < 2; ++nh)
#pragma unroll
        for (int r = 0; r < 4; ++r) { sc1[nh][r] = 0.f; sc2[nh][r] = 0.f; }

    for (int stp = 0; stp < 16; ++stp) {
        const int dc0 = stp * 32;
        f32x4 acc[2][2];
#pragma unroll
        for (int dh = 0; dh < 2; ++dh)
#pragma unroll
            for (int nh = 0; nh < 2; ++nh)
                acc[dh][nh] = (f32x4){0.f, 0.f, 0.f, 0.f};

#pragma unroll
        for (int dh = 0; dh < 2; ++dh) {
            const unsigned short* p = bpt + (size_t)(dc0 + dh * 16 + l15) * FIN + g * 8;
#pragma unroll
            for (int ks = 0; ks < 4; ++ks) {
                const bf16x8 af = *(const bf16x8*)(p + ks * 32);
                acc[dh][0] = __builtin_amdgcn_mfma_f32_16x16x32_bf16(af, xf[0][ks], acc[dh][0], 0, 0, 0);
                acc[dh][1] = __builtin_amdgcn_mfma_f32_16x16x32_bf16(af, xf[1][ks], acc[dh][1], 0, 0, 0);
            }
        }

#pragma unroll
        for (int dh = 0; dh < 2; ++dh) {
            const float4 ap1 = *(const float4*)&aperm[dc0 + dh * 16 + g * 4];
            const float4 ap2 = *(const float4*)&aperm[512 + dc0 + dh * 16 + g * 4];
#pragma unroll
            for (int nh = 0; nh < 2; ++nh) {
                sc1[nh][0] += acc[dh][nh][0] * ap1.x;  sc2[nh][0] += acc[dh][nh][0] * ap2.x;
                sc1[nh][1] += acc[dh][nh][1] * ap1.y;  sc2[nh][1] += acc[dh][nh][1] * ap2.y;
                sc1[nh][2] += acc[dh][nh][2] * ap1.z;  sc2[nh][2] += acc[dh][nh][2] * ap2.z;
                sc1[nh][3] += acc[dh][nh][3] * ap1.w;  sc2[nh][3] += acc[dh][nh][3] * ap2.w;
            }
        }

#pragma unroll
        for (int nh = 0; nh < 2; ++nh) {
            const int node = m0 + nh * 16 + l15;
            if (node < N_NODES) {
#pragma unroll
                for (int dh = 0; dh < 2; ++dh) {
                    const int dc = dc0 + dh * 16 + g * 4;
                    uint2 pk;
                    pk.x = pack_bf2(acc[dh][nh][0], acc[dh][nh][1]);
                    pk.y = pack_bf2(acc[dh][nh][2], acc[dh][nh][3]);
                    *(uint2*)((char*)h2 + ((size_t)node * HSTRIDE + dc) * 2) = pk;
                }
            }
        }
    }

#pragma unroll
    for (int nh = 0; nh < 2; ++nh) {
        const int node = m0 + nh * 16 + l15;
        float4 v1 = make_float4(sc1[nh][0], sc1[nh][1], sc1[nh][2], sc1[nh][3]);
        float4 v2 = make_float4(sc2[nh][0], sc2[nh][1], sc2[nh][2], sc2[nh][3]);
        v1.x += __shfl_xor(v1.x, 32, 64); v1.y += __shfl_xor(v1.y, 32, 64);
        v1.z += __shfl_xor(v1.z, 32, 64); v1.w += __shfl_xor(v1.w, 32, 64);
        v2.x += __shfl_xor(v2.x, 32, 64); v2.y += __shfl_xor(v2.y, 32, 64);
        v2.z += __shfl_xor(v2.z, 32, 64); v2.w += __shfl_xor(v2.w, 32, 64);
        if (node < N_NODES) {
            if (g == 0) { *(float4*)&ssrc[node * 8]     = v1; *(float4*)&sdst[node * 8]     = v2; }
            if (g == 1) { *(float4*)&ssrc[node * 8 + 4] = v1; *(float4*)&sdst[node * 8 + 4] = v2; }
        }
    }
}

// ---------------- Gather (unchanged from round 6): wave per node, 4-deep pipelined loads.
#define GAT_LD(KK) (*(const uint4*)(h2b + ((size_t)(unsigned)__builtin_amdgcn_readlane(d, (KK)) << 10) + lofs))

#define GAT_FMA(HV, KK) do {                                                          \
    const float e0 = __int_as_float(__builtin_amdgcn_readlane(__float_as_int(e[0]), (KK))); \
    const float e1 = __int_as_float(__builtin_amdgcn_readlane(__float_as_int(e[1]), (KK))); \
    const float e2 = __int_as_float(__builtin_amdgcn_readlane(__float_as_int(e[2]), (KK))); \
    const float e3 = __int_as_float(__builtin_amdgcn_readlane(__float_as_int(e[3]), (KK))); \
    const float e4 = __int_as_float(__builtin_amdgcn_readlane(__float_as_int(e[4]), (KK))); \
    const float e5 = __int_as_float(__builtin_amdgcn_readlane(__float_as_int(e[5]), (KK))); \
    const float e6 = __int_as_float(__builtin_amdgcn_readlane(__float_as_int(e[6]), (KK))); \
    const float e7 = __int_as_float(__builtin_amdgcn_readlane(__float_as_int(e[7]), (KK))); \
    acc[0] += e0 * __int_as_float((HV).x << 16);                                      \
    acc[1] += e1 * __int_as_float((HV).x & 0xFFFF0000u);                              \
    acc[2] += e2 * __int_as_float((HV).y << 16);                                      \
    acc[3] += e3 * __int_as_float((HV).y & 0xFFFF0000u);                              \
    acc[4] += e4 * __int_as_float((HV).z << 16);                                      \
    acc[5] += e5 * __int_as_float((HV).z & 0xFFFF0000u);                              \
    acc[6] += e6 * __int_as_float((HV).w << 16);                                      \
    acc[7] += e7 * __int_as_float((HV).w & 0xFFFF0000u);                              \
} while (0)

__global__ __launch_bounds__(256) void gat_gather(const int* __restrict__ row_start,
                                                  const int* __restrict__ csr_dst,
                                                  const __hip_bfloat16* __restrict__ h2,
                                                  const float* __restrict__ ssrc,
                                                  const float* __restrict__ sdst,
                                                  float* __restrict__ out) {
    const int n    = (int)((blockIdx.x * 256 + threadIdx.x) >> 6);
    const int lane = threadIdx.x & 63;
    if (n >= N_NODES) return;

    const int start = row_start[n];
    const int degn  = row_start[n + 1] - start;

    const float4 sa = *(const float4*)(ssrc + n * 8);
    const float4 sb = *(const float4*)(ssrc + n * 8 + 4);
    const float s0[8] = {sa.x, sa.y, sa.z, sa.w, sb.x, sb.y, sb.z, sb.w};

    float acc[8] = {0.f, 0.f, 0.f, 0.f, 0.f, 0.f, 0.f, 0.f};
    float rs[8]  = {0.f, 0.f, 0.f, 0.f, 0.f, 0.f, 0.f, 0.f};
    const unsigned lofs = (unsigned)lane * 16u;
    const char* h2b = (const char*)h2;

    for (int base = 0; base < degn; base += 64) {
        const int j      = base + lane;
        const bool valid = j < degn;
        const int d = valid ? __builtin_nontemporal_load(csr_dst + start + j) : 0;
        float4 qa = make_float4(0.f, 0.f, 0.f, 0.f), qb = qa;
        if (valid) {
            qa = *(const float4*)(sdst + d * 8);
            qb = *(const float4*)(sdst + d * 8 + 4);
        }
        const float q[8] = {qa.x, qa.y, qa.z, qa.w, qb.x, qb.y, qb.z, qb.w};
        float e[8];
#pragma unroll
        for (int i = 0; i < 8; ++i) {
            const float sv = s0[i] + q[i];
            const float lr = sv > 0.f ? sv : ALPHA * sv;
            e[i] = valid ? __expf(-lr) : 0.f;
            rs[i] += e[i];
        }

        const int cnt = min(64, degn - base);
        int k = 0;
        if (cnt >= 8) {
            uint4 q0 = GAT_LD(0), q1 = GAT_LD(1), q2 = GAT_LD(2), q3 = GAT_LD(3);
            for (k = 0; k + 8 <= cnt; k += 4) {
                GAT_FMA(q0, k + 0); q0 = GAT_LD(k + 4);
                GAT_FMA(q1, k + 1); q1 = GAT_LD(k + 5);
                GAT_FMA(q2, k + 2); q2 = GAT_LD(k + 6);
                GAT_FMA(q3, k + 3); q3 = GAT_LD(k + 7);
            }
            GAT_FMA(q0, k + 0);
            GAT_FMA(q1, k + 1);
            GAT_FMA(q2, k + 2);
            GAT_FMA(q3, k + 3);
            k += 4;
        }
        for (; k < cnt; ++k) {
            const uint4 qv = GAT_LD(k);
            GAT_FMA(qv, k);
        }
    }

#pragma unroll
    for (int i = 0; i < 8; ++i)
#pragma unroll
        for (int m = 1; m < 64; m <<= 1) rs[i] += __shfl_xor(rs[i], m, 64);

#pragma unroll
    for (int i = 0; i < 8; ++i)
        __builtin_nontemporal_store(acc[i] / rs[i], &out[(size_t)n * HSTRIDE + i * 64 + lane]);
}

extern "C" void kernel_launch(void* const* d_in, const int* in_sizes, int n_in,
                              void* d_out, int out_size, void* d_ws, size_t ws_size,
                              hipStream_t stream) {
    const float* x    = (const float*)d_in[0];
    const int*   edge = (const int*)d_in[1];
    const float* W    = (const float*)d_in[2];
    const float* a    = (const float*)d_in[3];
    float*       out  = (float*)d_out;

    char* ws = (char*)d_ws;
    size_t off = 0;
    unsigned short* h2  = (unsigned short*)(ws + off); off += (size_t)N_NODES * HSTRIDE * 2;
    unsigned short* xbf = (unsigned short*)(ws + off); off += (size_t)N_NODES * FIN * 2;
    unsigned short* bpt = (unsigned short*)(ws + off); off += (size_t)HSTRIDE * FIN * 2;
    float* aperm  = (float*)(ws + off); off += (size_t)2 * HSTRIDE * sizeof(float);
    float* ssrc   = (float*)(ws + off); off += (size_t)N_NODES * NH * sizeof(float);
    float* sdst   = (float*)(ws + off); off += (size_t)N_NODES * NH * sizeof(float);
    int*   row_st = (int*)  (ws + off); off += (size_t)(N_NODES + 4) * sizeof(int);
    int*   cursor = (int*)  (ws + off); off += (size_t)N_NODES * sizeof(int);
    int*   deg    = (int*)  (ws + off); off += (size_t)N_NODES * sizeof(int);
    int*   bsum   = (int*)  (ws + off); off += (size_t)256 * sizeof(int);
    int*   csrd   = (int*)  (ws + off); off += (size_t)N_EDGES * sizeof(int);

    const int* srcv = edge;
    const int* dstv = edge + N_EDGES;

    void* bargs[] = {(void*)&x, (void*)&W, (void*)&a, (void*)&srcv, (void*)&dstv,
                     (void*)&xbf, (void*)&bpt, (void*)&aperm, (void*)&deg,
                     (void*)&bsum, (void*)&row_st, (void*)&cursor, (void*)&csrd};
    hipLaunchCooperativeKernel((void*)gat_build, dim3(BUILD_GRID), dim3(256), bargs, 0, stream);

    gat_proj  <<<(N_NODES + 127) / 128, 256, 0, stream>>>(xbf, bpt, aperm, h2, ssrc, sdst);
    gat_gather<<<(N_NODES + 3) / 4, 256, 0, stream>>>(row_st, csrd, (const __hip_bfloat16*)h2, ssrc, sdst, out);
}

// Round 8
// 266.575 us; speedup vs baseline: 1.9676x; 1.9676x over previous
//
#include <hip/hip_runtime.h>
#include <hip/hip_bf16.h>
#include <math.h>

#define N_NODES 50000
#define N_EDGES 800000
#define FIN 128
#define FOUT 64
#define NH 8
#define ALPHA 0.2f
#define HSTRIDE (NH * FOUT)  // 512
#define SCAN_B 196           // ceil(50000/256)

// prep kernel block ranges
#define BPT_B  64            // 16384 threads
#define APERM_B 4            // 1024 threads
#define HIST_B 1563          // 2 edges/thread
#define PREP_B (BPT_B + APERM_B + HIST_B)

typedef __attribute__((ext_vector_type(8))) short bf16x8;
typedef __attribute__((ext_vector_type(4))) float f32x4;

__device__ __forceinline__ unsigned pack_bf2(float lo, float hi) {
    __hip_bfloat162 b = __float22bfloat162_rn(make_float2(lo, hi));
    return *(unsigned*)&b;
}

// ---------------- fused prep: W->BpT | a->aperm | degree histogram
__global__ __launch_bounds__(256) void gat_prep(const float* __restrict__ W,
                                                const float* __restrict__ a,
                                                const int* __restrict__ src,
                                                unsigned* __restrict__ bpt,
                                                float* __restrict__ aperm,
                                                int* __restrict__ deg) {
    const int b = blockIdx.x;
    const int t = threadIdx.x;

    if (b < BPT_B) {
        const int gt   = b * 256 + t;             // 16384
        const int dcol = gt >> 5;
        const int kq   = gt & 31;
        const int head = dcol & 7, col = dcol >> 3;
        const float* wp = W + (size_t)head * (FIN * FOUT) + (size_t)(kq * 4) * FOUT + col;
        uint2 pk;
        pk.x = pack_bf2(wp[0],        wp[FOUT]);
        pk.y = pack_bf2(wp[2 * FOUT], wp[3 * FOUT]);
        *(uint2*)(bpt + (size_t)dcol * (FIN / 2) + kq * 2) = pk;
    } else if (b < BPT_B + APERM_B) {
        const int idx  = (b - BPT_B) * 256 + t;   // 0..1023
        const int tab  = idx >> 9;                // 0 = src, 1 = dst
        const int dcol = idx & 511;
        aperm[idx] = a[(dcol & 7) * (2 * FOUT) + tab * FOUT + (dcol >> 3)];
    } else {
        const int e = ((b - BPT_B - APERM_B) * 256 + t) * 2;
        if (e + 1 < N_EDGES) {
            const int2 s2 = *(const int2*)(src + e);
            atomicAdd(&deg[s2.x], 1);
            atomicAdd(&deg[s2.y], 1);
        } else if (e < N_EDGES) {
            atomicAdd(&deg[src[e]], 1);
        }
    }
}

// ---------------- MFMA projection + fused scores. x read as f32, packed in-register.
// h2[n][col][head] bf16; ssrc/sdst[n][head] f32 from the f32 MFMA accumulators.
__global__ __launch_bounds__(256) void gat_proj(const float* __restrict__ x,
                                                const unsigned short* __restrict__ bpt,
                                                const float* __restrict__ aperm,
                                                unsigned short* __restrict__ h2,
                                                float* __restrict__ ssrc,
                                                float* __restrict__ sdst) {
    const int lane = threadIdx.x & 63;
    const int wid  = blockIdx.x * 4 + (threadIdx.x >> 6);
    const int m0   = wid * 32;
    const int l15  = lane & 15;
    const int g    = lane >> 4;

    bf16x8 xf[2][4];
#pragma unroll
    for (int nh = 0; nh < 2; ++nh) {
        int node = m0 + nh * 16 + l15;
        if (node > N_NODES - 1) node = N_NODES - 1;
        const float* p = x + (size_t)node * FIN + g * 8;
#pragma unroll
        for (int ks = 0; ks < 4; ++ks) {
            const float4 a0 = *(const float4*)(p + ks * 32);
            const float4 a1 = *(const float4*)(p + ks * 32 + 4);
            unsigned* u = (unsigned*)&xf[nh][ks];
            u[0] = pack_bf2(a0.x, a0.y);
            u[1] = pack_bf2(a0.z, a0.w);
            u[2] = pack_bf2(a1.x, a1.y);
            u[3] = pack_bf2(a1.z, a1.w);
        }
    }

    float sc1[2][4], sc2[2][4];
#pragma unroll
    for (int nh = 0; nh < 2; ++nh)
#pragma unroll
        for (int r = 0; r < 4; ++r) { sc1[nh][r] = 0.f; sc2[nh][r] = 0.f; }

    for (int stp = 0; stp < 16; ++stp) {
        const int dc0 = stp * 32;
        f32x4 acc[2][2];
#pragma unroll
        for (int dh = 0; dh < 2; ++dh)
#pragma unroll
            for (int nh = 0; nh < 2; ++nh)
                acc[dh][nh] = (f32x4){0.f, 0.f, 0.f, 0.f};

#pragma unroll
        for (int dh = 0; dh < 2; ++dh) {
            const unsigned short* p = bpt + (size_t)(dc0 + dh * 16 + l15) * FIN + g * 8;
#pragma unroll
            for (int ks = 0; ks < 4; ++ks) {
                const bf16x8 af = *(const bf16x8*)(p + ks * 32);
                acc[dh][0] = __builtin_amdgcn_mfma_f32_16x16x32_bf16(af, xf[0][ks], acc[dh][0], 0, 0, 0);
                acc[dh][1] = __builtin_amdgcn_mfma_f32_16x16x32_bf16(af, xf[1][ks], acc[dh][1], 0, 0, 0);
            }
        }

#pragma unroll
        for (int dh = 0; dh < 2; ++dh) {
            const float4 ap1 = *(const float4*)&aperm[dc0 + dh * 16 + g * 4];
            const float4 ap2 = *(const float4*)&aperm[512 + dc0 + dh * 16 + g * 4];
#pragma unroll
            for (int nh = 0; nh < 2; ++nh) {
                sc1[nh][0] += acc[dh][nh][0] * ap1.x;  sc2[nh][0] += acc[dh][nh][0] * ap2.x;
                sc1[nh][1] += acc[dh][nh][1] * ap1.y;  sc2[nh][1] += acc[dh][nh][1] * ap2.y;
                sc1[nh][2] += acc[dh][nh][2] * ap1.z;  sc2[nh][2] += acc[dh][nh][2] * ap2.z;
                sc1[nh][3] += acc[dh][nh][3] * ap1.w;  sc2[nh][3] += acc[dh][nh][3] * ap2.w;
            }
        }

#pragma unroll
        for (int nh = 0; nh < 2; ++nh) {
            const int node = m0 + nh * 16 + l15;
            if (node < N_NODES) {
#pragma unroll
                for (int dh = 0; dh < 2; ++dh) {
                    const int dc = dc0 + dh * 16 + g * 4;
                    uint2 pk;
                    pk.x = pack_bf2(acc[dh][nh][0], acc[dh][nh][1]);
                    pk.y = pack_bf2(acc[dh][nh][2], acc[dh][nh][3]);
                    *(uint2*)((char*)h2 + ((size_t)node * HSTRIDE + dc) * 2) = pk;
                }
            }
        }
    }

#pragma unroll
    for (int nh = 0; nh < 2; ++nh) {
        const int node = m0 + nh * 16 + l15;
        float4 v1 = make_float4(sc1[nh][0], sc1[nh][1], sc1[nh][2], sc1[nh][3]);
        float4 v2 = make_float4(sc2[nh][0], sc2[nh][1], sc2[nh][2], sc2[nh][3]);
        v1.x += __shfl_xor(v1.x, 32, 64); v1.y += __shfl_xor(v1.y, 32, 64);
        v1.z += __shfl_xor(v1.z, 32, 64); v1.w += __shfl_xor(v1.w, 32, 64);
        v2.x += __shfl_xor(v2.x, 32, 64); v2.y += __shfl_xor(v2.y, 32, 64);
        v2.z += __shfl_xor(v2.z, 32, 64); v2.w += __shfl_xor(v2.w, 32, 64);
        if (node < N_NODES) {
            if (g == 0) { *(float4*)&ssrc[node * 8]     = v1; *(float4*)&sdst[node * 8]     = v2; }
            if (g == 1) { *(float4*)&ssrc[node * 8 + 4] = v1; *(float4*)&sdst[node * 8 + 4] = v2; }
        }
    }
}

// ---------------- scan stage 1: per-256-segment sums
__global__ __launch_bounds__(256) void scan_bsum(const int* __restrict__ deg,
                                                 int* __restrict__ bsum) {
    __shared__ int sm[256];
    const int t   = threadIdx.x;
    const int gid = blockIdx.x * 256 + t;
    sm[t] = (gid < N_NODES) ? deg[gid] : 0;
    __syncthreads();
#pragma unroll
    for (int off = 128; off > 0; off >>= 1) {
        if (t < off) sm[t] += sm[t + off];
        __syncthreads();
    }
    if (t == 0) bsum[blockIdx.x] = sm[0];
}

// ---------------- scan stage 2 (merged): redundant partial-scan + segment scan
__global__ __launch_bounds__(256) void scan_write(const int* __restrict__ deg,
                                                  const int* __restrict__ bsum,
                                                  int* __restrict__ row_start,
                                                  int* __restrict__ cursor) {
    __shared__ int smp[256];
    __shared__ int sm[256];
    const int t = threadIdx.x;
    const int b = blockIdx.x;

    // redundant exclusive-prefix of the 196 block sums
    const int pv = (t < SCAN_B) ? bsum[t] : 0;
    smp[t] = pv;
    __syncthreads();
    for (int off = 1; off < 256; off <<= 1) {
        const int u = (t >= off) ? smp[t - off] : 0;
        __syncthreads();
        smp[t] += u;
        __syncthreads();
    }
    const int base = (b > 0) ? smp[b - 1] : 0;

    const int gid = b * 256 + t;
    const int v   = (gid < N_NODES) ? deg[gid] : 0;
    sm[t] = v;
    __syncthreads();
    for (int off = 1; off < 256; off <<= 1) {
        const int u = (t >= off) ? sm[t - off] : 0;
        __syncthreads();
        sm[t] += u;
        __syncthreads();
    }
    if (gid < N_NODES) {
        const int rs = base + sm[t] - v;
        row_start[gid] = rs;
        cursor[gid]    = rs;
    }
    if (b == 0 && t == 0) row_start[N_NODES] = N_EDGES;
}

__global__ __launch_bounds__(256) void gat_fill(const int* __restrict__ src,
                                                const int* __restrict__ dst,
                                                int* __restrict__ cursor,
                                                int* __restrict__ csr_dst) {
    const int e = blockIdx.x * 256 + threadIdx.x;
    if (e >= N_EDGES) return;
    const int pos = atomicAdd(&cursor[src[e]], 1);
    csr_dst[pos] = dst[e];
}

// ---------------- Gather (unchanged): wave per node, 4-deep pipelined h2 loads.
#define GAT_LD(KK) (*(const uint4*)(h2b + ((size_t)(unsigned)__builtin_amdgcn_readlane(d, (KK)) << 10) + lofs))

#define GAT_FMA(HV, KK) do {                                                          \
    const float e0 = __int_as_float(__builtin_amdgcn_readlane(__float_as_int(e[0]), (KK))); \
    const float e1 = __int_as_float(__builtin_amdgcn_readlane(__float_as_int(e[1]), (KK))); \
    const float e2 = __int_as_float(__builtin_amdgcn_readlane(__float_as_int(e[2]), (KK))); \
    const float e3 = __int_as_float(__builtin_amdgcn_readlane(__float_as_int(e[3]), (KK))); \
    const float e4 = __int_as_float(__builtin_amdgcn_readlane(__float_as_int(e[4]), (KK))); \
    const float e5 = __int_as_float(__builtin_amdgcn_readlane(__float_as_int(e[5]), (KK))); \
    const float e6 = __int_as_float(__builtin_amdgcn_readlane(__float_as_int(e[6]), (KK))); \
    const float e7 = __int_as_float(__builtin_amdgcn_readlane(__float_as_int(e[7]), (KK))); \
    acc[0] += e0 * __int_as_float((HV).x << 16);                                      \
    acc[1] += e1 * __int_as_float((HV).x & 0xFFFF0000u);                              \
    acc[2] += e2 * __int_as_float((HV).y << 16);                                      \
    acc[3] += e3 * __int_as_float((HV).y & 0xFFFF0000u);                              \
    acc[4] += e4 * __int_as_float((HV).z << 16);                                      \
    acc[5] += e5 * __int_as_float((HV).z & 0xFFFF0000u);                              \
    acc[6] += e6 * __int_as_float((HV).w << 16);                                      \
    acc[7] += e7 * __int_as_float((HV).w & 0xFFFF0000u);                              \
} while (0)

__global__ __launch_bounds__(256) void gat_gather(const int* __restrict__ row_start,
                                                  const int* __restrict__ csr_dst,
                                                  const __hip_bfloat16* __restrict__ h2,
                                                  const float* __restrict__ ssrc,
                                                  const float* __restrict__ sdst,
                                                  float* __restrict__ out) {
    const int n    = (int)((blockIdx.x * 256 + threadIdx.x) >> 6);
    const int lane = threadIdx.x & 63;
    if (n >= N_NODES) return;

    const int start = row_start[n];
    const int degn  = row_start[n + 1] - start;

    const float4 sa = *(const float4*)(ssrc + n * 8);
    const float4 sb = *(const float4*)(ssrc + n * 8 + 4);
    const float s0[8] = {sa.x, sa.y, sa.z, sa.w, sb.x, sb.y, sb.z, sb.w};

    float acc[8] = {0.f, 0.f, 0.f, 0.f, 0.f, 0.f, 0.f, 0.f};
    float rs[8]  = {0.f, 0.f, 0.f, 0.f, 0.f, 0.f, 0.f, 0.f};
    const unsigned lofs = (unsigned)lane * 16u;
    const char* h2b = (const char*)h2;

    for (int base = 0; base < degn; base += 64) {
        const int j      = base + lane;
        const bool valid = j < degn;
        const int d = valid ? __builtin_nontemporal_load(csr_dst + start + j) : 0;
        float4 qa = make_float4(0.f, 0.f, 0.f, 0.f), qb = qa;
        if (valid) {
            qa = *(const float4*)(sdst + d * 8);
            qb = *(const float4*)(sdst + d * 8 + 4);
        }
        const float q[8] = {qa.x, qa.y, qa.z, qa.w, qb.x, qb.y, qb.z, qb.w};
        float e[8];
#pragma unroll
        for (int i = 0; i < 8; ++i) {
            const float sv = s0[i] + q[i];
            const float lr = sv > 0.f ? sv : ALPHA * sv;
            e[i] = valid ? __expf(-lr) : 0.f;
            rs[i] += e[i];
        }

        const int cnt = min(64, degn - base);
        int k = 0;
        if (cnt >= 8) {
            uint4 q0 = GAT_LD(0), q1 = GAT_LD(1), q2 = GAT_LD(2), q3 = GAT_LD(3);
            for (k = 0; k + 8 <= cnt; k += 4) {
                GAT_FMA(q0, k + 0); q0 = GAT_LD(k + 4);
                GAT_FMA(q1, k + 1); q1 = GAT_LD(k + 5);
                GAT_FMA(q2, k + 2); q2 = GAT_LD(k + 6);
                GAT_FMA(q3, k + 3); q3 = GAT_LD(k + 7);
            }
            GAT_FMA(q0, k + 0);
            GAT_FMA(q1, k + 1);
            GAT_FMA(q2, k + 2);
            GAT_FMA(q3, k + 3);
            k += 4;
        }
        for (; k < cnt; ++k) {
            const uint4 qv = GAT_LD(k);
            GAT_FMA(qv, k);
        }
    }

#pragma unroll
    for (int i = 0; i < 8; ++i)
#pragma unroll
        for (int m = 1; m < 64; m <<= 1) rs[i] += __shfl_xor(rs[i], m, 64);

#pragma unroll
    for (int i = 0; i < 8; ++i)
        __builtin_nontemporal_store(acc[i] / rs[i], &out[(size_t)n * HSTRIDE + i * 64 + lane]);
}

extern "C" void kernel_launch(void* const* d_in, const int* in_sizes, int n_in,
                              void* d_out, int out_size, void* d_ws, size_t ws_size,
                              hipStream_t stream) {
    const float* x    = (const float*)d_in[0];
    const int*   edge = (const int*)d_in[1];
    const float* W    = (const float*)d_in[2];
    const float* a    = (const float*)d_in[3];
    float*       out  = (float*)d_out;

    char* ws = (char*)d_ws;
    size_t off = 0;
    unsigned short* h2  = (unsigned short*)(ws + off); off += (size_t)N_NODES * HSTRIDE * 2;
    unsigned short* bpt = (unsigned short*)(ws + off); off += (size_t)HSTRIDE * FIN * 2;
    float* aperm  = (float*)(ws + off); off += (size_t)2 * HSTRIDE * sizeof(float);
    float* ssrc   = (float*)(ws + off); off += (size_t)N_NODES * NH * sizeof(float);
    float* sdst   = (float*)(ws + off); off += (size_t)N_NODES * NH * sizeof(float);
    int*   row_st = (int*)  (ws + off); off += (size_t)(N_NODES + 4) * sizeof(int);
    int*   cursor = (int*)  (ws + off); off += (size_t)N_NODES * sizeof(int);
    int*   deg    = (int*)  (ws + off); off += (size_t)N_NODES * sizeof(int);
    int*   bsum   = (int*)  (ws + off); off += (size_t)256 * sizeof(int);
    int*   csrd   = (int*)  (ws + off); off += (size_t)N_EDGES * sizeof(int);

    const int* srcv = edge;
    const int* dstv = edge + N_EDGES;

    hipMemsetAsync(deg, 0, (size_t)N_NODES * sizeof(int), stream);

    gat_prep  <<<PREP_B, 256, 0, stream>>>(W, a, srcv, (unsigned*)bpt, aperm, deg);
    scan_bsum <<<SCAN_B, 256, 0, stream>>>(deg, bsum);
    scan_write<<<SCAN_B, 256, 0, stream>>>(deg, bsum, row_st, cursor);
    gat_fill  <<<(N_EDGES + 255) / 256, 256, 0, stream>>>(srcv, dstv, cursor, csrd);
    gat_proj  <<<(N_NODES + 127) / 128, 256, 0, stream>>>(x, bpt, aperm, h2, ssrc, sdst);
    gat_gather<<<(N_NODES + 3) / 4, 256, 0, stream>>>(row_st, csrd, (const __hip_bfloat16*)h2, ssrc, sdst, out);
}